// Round 23
// baseline (38.026 us; speedup 1.0000x reference)
//
#include <hip/hip_runtime.h>

#define Oo    32
#define F2    4096
#define GRID  256            // (oq:8) x (hh:32) -> 1 block/CU
#define SLOTS 32             // per-o partial slots: one per hh block
#define NTOT  (32 * F2)

typedef _Float16 h2 __attribute__((ext_vector_type(2)));
typedef _Float16 h8 __attribute__((ext_vector_type(8)));

#if __has_builtin(__builtin_amdgcn_fdot2)
#define DOT2(a, b, c) __builtin_amdgcn_fdot2((a), (b), (c), false)
#else
__device__ __forceinline__ float DOT2(h2 a, h2 b, float c) {
    return c + (float)a.x * (float)b.x + (float)a.y * (float)b.y;
}
#endif

__device__ __forceinline__ unsigned pkh2f(float a, float b) {
    h2 t; t.x = (_Float16)a; t.y = (_Float16)b;
    return __builtin_bit_cast(unsigned, t);
}
__device__ __forceinline__ h2 bch2(unsigned u) { return __builtin_bit_cast(h2, u); }

// TWO-ROW TILE: r16's DRAM-contiguity lever doubled. Block = 4 o's x rows
// {2hh,2hh+1} x 64 cols x 32 batches; grid 256 = (oq:8)x(hh:32). Weight
// reads: 512B contiguous runs (128 cols); x reads: 1KB runs (4 consecutive
// image rows are memory-contiguous). Per-CU LDS-instr and VALU totals are
// UNCHANGED vs r22 (work/block x2, blocks /2) -> isolated test of the
// DRAM-run-length hypothesis for the ~3TB/s plateau. Thread = (bq:8)x(f:64),
// acc[o:4][r:2][i:4]; LDS 71.7KB (x 34.8 + w 2x18.4); r21 schedule and
// channel-pair numerics verbatim; 2-dispatch tail (psum SLOTS=32).
template <typename YT>
__global__ __launch_bounds__(512) void svconv_kernel(
    const float* __restrict__ x, const float* __restrict__ wgt,
    const float* __restrict__ bias, YT* __restrict__ y,
    float* __restrict__ psum, float* __restrict__ psumsq)
{
    __shared__ __align__(16) unsigned ldsX[4 * 32 * 68];      // [khr][b][w'] 34.8KB
    __shared__ __align__(16) unsigned ldsW[2 * 9 * 4 * 128];  // [buf][k][o][c] 36.9KB

    const int tid = threadIdx.x;
    const int f   = tid & 63;
    const int bq  = tid >> 6;                 // 0..7 (= wave id)
    const int oq  = blockIdx.x >> 5;          // 0..7
    const int hh  = blockIdx.x & 31;          // 0..31
    const int h0  = 2 * hh;

    // ---- weight slots: s = tid + m*512 over 1152 = (o:4)x(k:9)x(q:32) ----
    // slot loads cols hh*128 + 4q .. +3 for p = 18cp+k (wA) and +9 (wB):
    // per (o,k) the 32 q-slots cover 512B CONTIGUOUS DRAM.
    bool wOKm[3];
    int  wg[3], wl[3];
#pragma unroll
    for (int m = 0; m < 3; ++m) {
        int s = tid + m * 512;
        wOKm[m] = (s < 1152);
        if (!wOKm[m]) s = 0;
        int o_ = s / 288, rm = s - 288 * o_;
        int k_ = rm >> 5, q_ = rm & 31;
        wg[m] = ((oq * 4 + o_) * 72 + k_) * F2 + hh * 128 + 4 * q_;  // +cp*18*F2; pair +9*F2
        wl[m] = (k_ * 4 + o_) * 128 + 4 * q_;
    }

    // ---- x slots: s = tid + m*512 over 2048 = (b:32)x(khr:4)x(q:16) ----
    // per (b,channel) the 64 (khr,q)-slots cover 4 rows = 1KB CONTIGUOUS.
    bool xOKm[4];
    int  xg[4], xl[4];
#pragma unroll
    for (int m = 0; m < 4; ++m) {
        int s = tid + m * 512;
        int b_ = s >> 6, rm = s & 63;
        int khr = rm >> 4, q = rm & 15;
        int gh = h0 - 1 + khr;
        xOKm[m] = ((unsigned)gh < 64u);
        xg[m] = b_ * 32768 + gh * 64 + 4 * q;          // + c*4096 at issue
        xl[m] = (khr * 32 + b_) * 68 + 4 * q;
    }

    // x tap indices (halo cols at w'=64 (left) and 65 (right), zero forever)
    const int wi0 = (f == 0)  ? 64 : f - 1;
    const int wi2 = (f == 63) ? 65 : f + 1;

    float bz[4][2];
#pragma unroll
    for (int j = 0; j < 4; ++j)
#pragma unroll
        for (int r = 0; r < 2; ++r)
            bz[j][r] = bias[(oq * 4 + j) * F2 + (h0 + r) * 64 + f];

    float acc[4][2][4];
#pragma unroll
    for (int j = 0; j < 4; ++j)
#pragma unroll
        for (int r = 0; r < 2; ++r)
#pragma unroll
            for (int i = 0; i < 4; ++i) acc[j][r][i] = 0.f;

    float4 xr0[4], xr1[4], wr0[3], wr1[3];    // staged regs (one chunk in flight)

    auto ISSUEX = [&](int cp) {
        const int co = cp * 8192;              // ch0 = 2cp*4096
#pragma unroll
        for (int m = 0; m < 4; ++m) {
            if (xOKm[m]) {
                xr0[m] = *(const float4*)(x + xg[m] + co);
                xr1[m] = *(const float4*)(x + xg[m] + co + 4096);
            } else {
                xr0[m] = make_float4(0.f, 0.f, 0.f, 0.f);
                xr1[m] = xr0[m];
            }
        }
    };
    auto ISSUEW = [&](int cp) {
        const int off = cp * 18 * F2;
#pragma unroll
        for (int m = 0; m < 3; ++m)
            if (wOKm[m]) {
                wr0[m] = *(const float4*)(wgt + wg[m] + off);
                wr1[m] = *(const float4*)(wgt + wg[m] + off + 9 * F2);
            }
    };
    auto WRITEX = [&]() {
#pragma unroll
        for (int m = 0; m < 4; ++m) {
            uint4 pk;
            pk.x = pkh2f(xr0[m].x, xr1[m].x);
            pk.y = pkh2f(xr0[m].y, xr1[m].y);
            pk.z = pkh2f(xr0[m].z, xr1[m].z);
            pk.w = pkh2f(xr0[m].w, xr1[m].w);
            *(uint4*)&ldsX[xl[m]] = pk;
        }
    };
    auto WRITEW = [&](int buf) {
#pragma unroll
        for (int m = 0; m < 3; ++m)
            if (wOKm[m]) {
                uint4 pk;
                pk.x = pkh2f(wr0[m].x, wr1[m].x);
                pk.y = pkh2f(wr0[m].y, wr1[m].y);
                pk.z = pkh2f(wr0[m].z, wr1[m].z);
                pk.w = pkh2f(wr0[m].w, wr1[m].w);
                *(uint4*)&ldsW[buf * 4608 + wl[m]] = pk;
            }
    };
    auto COMPUTE = [&](int wbuf) {
        const unsigned* wb = &ldsW[wbuf * 4608];
#pragma unroll
        for (int k = 0; k < 9; ++k) {
            const int kh = k / 3, kw = k - 3 * kh;
            const int wi = (kw == 0) ? wi0 : ((kw == 1) ? f : wi2);
            h2 wv[4][2];
#pragma unroll
            for (int j = 0; j < 4; ++j)
#pragma unroll
                for (int r = 0; r < 2; ++r)
                    wv[j][r] = bch2(wb[(k * 4 + j) * 128 + r * 64 + f]);
#pragma unroll
            for (int r = 0; r < 2; ++r)
#pragma unroll
                for (int i = 0; i < 4; ++i) {
                    h2 xv = bch2(ldsX[((kh + r) * 32 + bq * 4 + i) * 68 + wi]);
#pragma unroll
                    for (int j = 0; j < 4; ++j)
                        acc[j][r][i] = DOT2(wv[j][r], xv, acc[j][r][i]);
                }
        }
    };

    // ---- prologue: zero x LDS (halo cols/rows stay zero); chunk0 staged ----
    ISSUEX(0); ISSUEW(0);
    for (int i = tid; i < 4 * 32 * 68; i += 512) ldsX[i] = 0u;
    __syncthreads();                       // drains ISSUE(0) (unavoidable once)
    WRITEX(); WRITEW(0);
    __syncthreads();                       // chunk0 visible
    ISSUEX(1); ISSUEW(1);                  // overlaps COMPUTE(0)

#pragma unroll
    for (int cp = 0; cp < 4; ++cp) {
        COMPUTE(cp & 1);                   // prefetch (cp+1) lands during this
        if (cp < 3) {
            __syncthreads();               // x reads done
            WRITEX(); WRITEW((cp + 1) & 1);
            __syncthreads();               // writes visible
            if (cp < 2) { ISSUEX(cp + 2); ISSUEW(cp + 2); }
        }
    }
    __syncthreads();                       // free ldsX for scratch reuse

    // ---- epilogue: bias, y store, BN partials ----
    float s_[4], ss_[4];
#pragma unroll
    for (int j = 0; j < 4; ++j) { s_[j] = 0.f; ss_[j] = 0.f; }
#pragma unroll
    for (int j = 0; j < 4; ++j)
#pragma unroll
        for (int r = 0; r < 2; ++r) {
            const int col = (h0 + r) * 64 + f;
#pragma unroll
            for (int i = 0; i < 4; ++i) {
                float a = acc[j][r][i] + bz[j][r];
                y[(size_t)((bq * 4 + i) * Oo + oq * 4 + j) * F2 + col] = (YT)a;
                s_[j] += a; ss_[j] = fmaf(a, a, ss_[j]);
            }
        }
    if (psum != nullptr) {
#pragma unroll
        for (int j = 0; j < 4; ++j)
#pragma unroll
            for (int d = 32; d >= 1; d >>= 1) {
                s_[j]  += __shfl_down(s_[j],  d, 64);
                ss_[j] += __shfl_down(ss_[j], d, 64);
            }
        float* scr = (float*)ldsX;          // [2][bq:8][o:4]
        if (f == 0) {
#pragma unroll
            for (int j = 0; j < 4; ++j) {
                scr[bq * 4 + j]      = s_[j];
                scr[32 + bq * 4 + j] = ss_[j];
            }
        }
        __syncthreads();
        if (tid < 32) {
            int j = tid >> 3, g = tid & 7;  // j = o-local, g = bq
            float v  = scr[g * 4 + j];
            float vv = scr[32 + g * 4 + j];
#pragma unroll
            for (int d = 4; d >= 1; d >>= 1) {
                v  += __shfl_down(v,  d, 8);
                vv += __shfl_down(vv, d, 8);
            }
            if (g == 0) {
                psum[(oq * 4 + j) * SLOTS + hh]   = v;
                psumsq[(oq * 4 + j) * SLOTS + hh] = vv;
            }
        }
    }
}

// ---- fused stats+apply: each block serves one o; 32 lanes reduce psum ----
__global__ __launch_bounds__(256) void bnapply_fused_kernel(
    const _Float16* __restrict__ yh, const float* __restrict__ psum,
    const float* __restrict__ psumsq, const float* __restrict__ gamma,
    const float* __restrict__ beta, float* __restrict__ y)
{
    __shared__ float scsh[2];
    const int o = (blockIdx.x >> 1) & 31;      // constant per block
    const int t = threadIdx.x;
    if (t < 32) {
        float v  = psum[o * SLOTS + t];
        float vv = psumsq[o * SLOTS + t];
#pragma unroll
        for (int d = 16; d >= 1; d >>= 1) {
            v  += __shfl_down(v,  d, 32);
            vv += __shfl_down(vv, d, 32);
        }
        if (t == 0) {
            float mean = v / (float)NTOT;
            float var  = vv / (float)NTOT - mean * mean;
            float rstd = rsqrtf(var + 1e-5f);
            float scl  = gamma[o] * rstd;
            scsh[0] = scl;
            scsh[1] = beta[o] - mean * scl;
        }
    }
    __syncthreads();
    const float scl = scsh[0], sh = scsh[1];

    int i = blockIdx.x * 256 + t;              // 8-element packs; 524288 total
    h8 v = ((const h8*)yh)[i];
    float4 lo, hi;
    lo.x = fmaf((float)v[0], scl, sh);
    lo.y = fmaf((float)v[1], scl, sh);
    lo.z = fmaf((float)v[2], scl, sh);
    lo.w = fmaf((float)v[3], scl, sh);
    hi.x = fmaf((float)v[4], scl, sh);
    hi.y = fmaf((float)v[5], scl, sh);
    hi.z = fmaf((float)v[6], scl, sh);
    hi.w = fmaf((float)v[7], scl, sh);
    ((float4*)y)[2 * i]     = lo;
    ((float4*)y)[2 * i + 1] = hi;
}

// ======== fallback kernels ========
__global__ __launch_bounds__(64) void bnstats_kernel(
    const float* __restrict__ psum, const float* __restrict__ psumsq,
    const float* __restrict__ gamma, const float* __restrict__ beta,
    float* __restrict__ scsh)
{
    const int o = blockIdx.x;
    const int t = threadIdx.x;
    float s = 0.f, ss = 0.f;
    if (t < SLOTS) { s = psum[o * SLOTS + t]; ss = psumsq[o * SLOTS + t]; }
#pragma unroll
    for (int d = 32; d >= 1; d >>= 1) {
        s  += __shfl_down(s, d, 64);
        ss += __shfl_down(ss, d, 64);
    }
    if (t == 0) {
        float mean = s / (float)NTOT;
        float var  = ss / (float)NTOT - mean * mean;
        float rstd = rsqrtf(var + 1e-5f);
        float scl  = gamma[o] * rstd;
        scsh[o]      = scl;
        scsh[Oo + o] = beta[o] - mean * scl;
    }
}

__global__ __launch_bounds__(256) void bnapply_kernel(
    float* __restrict__ y, const float* __restrict__ scsh)
{
    int i = blockIdx.x * 256 + threadIdx.x;    // float4 index
    float4 v = ((const float4*)y)[i];
    int o = (i >> 10) & 31;
    float scl = scsh[o], sh = scsh[Oo + o];
    v.x = fmaf(v.x, scl, sh);
    v.y = fmaf(v.y, scl, sh);
    v.z = fmaf(v.z, scl, sh);
    v.w = fmaf(v.w, scl, sh);
    ((float4*)y)[i] = v;
}

__global__ __launch_bounds__(256) void bnreduce_y_kernel(
    const float* __restrict__ y, float* __restrict__ seg, float* __restrict__ segsq)
{
    const int o  = blockIdx.x >> 3;
    const int sg = blockIdx.x & 7;
    const int t  = threadIdx.x;
    float s = 0.f, ss = 0.f;
    for (int i = t; i < 4 * 1024; i += 256) {
        int b   = sg * 4 + (i >> 10);
        int fof = (i & 1023) * 4;
        float4 v = *(const float4*)(y + (size_t)(b * Oo + o) * F2 + fof);
        s  += (v.x + v.y) + (v.z + v.w);
        ss += v.x * v.x + v.y * v.y + v.z * v.z + v.w * v.w;
    }
#pragma unroll
    for (int d = 32; d >= 1; d >>= 1) {
        s  += __shfl_down(s, d, 64);
        ss += __shfl_down(ss, d, 64);
    }
    __shared__ float ls[4], lss[4];
    int wv = t >> 6, ln = t & 63;
    if (ln == 0) { ls[wv] = s; lss[wv] = ss; }
    __syncthreads();
    if (t == 0) {
        seg[blockIdx.x]   = (ls[0] + ls[1]) + (ls[2] + ls[3]);
        segsq[blockIdx.x] = (lss[0] + lss[1]) + (lss[2] + lss[3]);
    }
}

__global__ __launch_bounds__(256) void bnstats2_kernel(
    const float* __restrict__ seg, const float* __restrict__ segsq,
    const float* __restrict__ gamma, const float* __restrict__ beta,
    float* __restrict__ scsh)
{
    const int t = threadIdx.x;
    const int o = t >> 3, g = t & 7;
    float v  = seg[t];
    float vv = segsq[t];
#pragma unroll
    for (int d = 4; d >= 1; d >>= 1) {
        v  += __shfl_down(v,  d, 8);
        vv += __shfl_down(vv, d, 8);
    }
    if (g == 0) {
        float mean = v / (float)NTOT;
        float var  = vv / (float)NTOT - mean * mean;
        float rstd = rsqrtf(var + 1e-5f);
        float scl  = gamma[o] * rstd;
        scsh[o]      = scl;
        scsh[Oo + o] = beta[o] - mean * scl;
    }
}

extern "C" void kernel_launch(void* const* d_in, const int* in_sizes, int n_in,
                              void* d_out, int out_size, void* d_ws, size_t ws_size,
                              hipStream_t stream)
{
    const float* x     = (const float*)d_in[0];
    const float* wgt   = (const float*)d_in[1];
    const float* bias  = (const float*)d_in[2];
    const float* gamma = (const float*)d_in[3];
    const float* beta  = (const float*)d_in[4];
    float* y = (float*)d_out;

    const size_t n_elems    = (size_t)NTOT * Oo;              // 4,194,304
    const size_t yh_bytes   = n_elems * sizeof(_Float16);     // 8 MiB
    const size_t psum_bytes = (size_t)(2 * Oo * SLOTS + 2 * Oo) * sizeof(float);

    if (ws_size >= yh_bytes + psum_bytes) {
        // primary: f16 intermediate y in ws; 2 dispatches
        _Float16* yh  = (_Float16*)d_ws;
        float* psum   = (float*)((char*)d_ws + yh_bytes);     // [Oo][SLOTS]
        float* psumsq = psum + Oo * SLOTS;
        svconv_kernel<_Float16><<<GRID, 512, 0, stream>>>(x, wgt, bias, yh, psum, psumsq);
        bnapply_fused_kernel<<<(int)(n_elems / 8 / 256), 256, 0, stream>>>(
            yh, psum, psumsq, gamma, beta, y);
    } else if (ws_size >= psum_bytes) {
        // secondary: fp32 y in d_out, partials in ws
        float* psum   = (float*)d_ws;
        float* psumsq = psum + Oo * SLOTS;
        float* scsh   = psumsq + Oo * SLOTS;
        svconv_kernel<float><<<GRID, 512, 0, stream>>>(x, wgt, bias, y, psum, psumsq);
        bnstats_kernel<<<Oo, 64, 0, stream>>>(psum, psumsq, gamma, beta, scsh);
        bnapply_kernel<<<(int)(n_elems / 4 / 256), 256, 0, stream>>>(y, scsh);
    } else {
        // tertiary: tiny scratch — reduce y directly
        float* seg   = (float*)d_ws;                          // [256]
        float* segsq = seg + 256;
        float* scsh  = segsq + 256;
        svconv_kernel<float><<<GRID, 512, 0, stream>>>(x, wgt, bias, y, nullptr, nullptr);
        bnreduce_y_kernel<<<256, 256, 0, stream>>>(y, seg, segsq);
        bnstats2_kernel<<<1, 256, 0, stream>>>(seg, segsq, gamma, beta, scsh);
        bnapply_kernel<<<(int)(n_elems / 4 / 256), 256, 0, stream>>>(y, scsh);
    }
}